// Round 1
// baseline (201.463 us; speedup 1.0000x reference)
//
#include <hip/hip_runtime.h>
#include <math.h>

#define N_AGENTS 1024
#define HID      128
#define SGRID    32        // S
#define NCELL    1024      // S*S
#define KDIM     2048      // HID * NGRID * NGRID
#define OUT_DIM  128

// ---------------------------------------------------------------------------
// Kernel 1: per-ego social pooling.
// Reference semantics: occ.at[i, cell, :].set(hidden[j]) -- duplicate cells
// resolve to the LAST writer in index order (numpy/XLA-CPU scatter), i.e. the
// max j. We reproduce that with atomicMax into a per-cell winner table (LDS),
// then sum the winners' hidden vectors into the 16 pooled blocks.
// P[i][h*16 + g] with g = gi*4 + gj  (matches channel-first flatten / W cols).
// ---------------------------------------------------------------------------
__global__ __launch_bounds__(128) void pool_kernel(
    const float* __restrict__ hidden,
    const float* __restrict__ obs2,
    float* __restrict__ P) {
  const int i = blockIdx.x;
  const int t = threadIdx.x;
  __shared__ int   win[NCELL];
  __shared__ int   s_cnt;
  __shared__ short s_g[NCELL];
  __shared__ short s_j[NCELL];

  for (int c = t; c < NCELL; c += 128) win[c] = -1;
  if (t == 0) s_cnt = 0;
  const float2* o2 = (const float2*)obs2;
  const float2 oi = o2[i];
  __syncthreads();

  // scatter: winner per cell = max valid j (last-writer-wins)
  for (int j = t; j < N_AGENTS; j += 128) {
    if (j == i) continue;
    float2 oj = o2[j];
    // oij = (obs2[j]-obs2[i]) / 0.25 + 16 ; /0.25 is exact *4.0
    float fx = (oj.x - oi.x) * 4.0f + 16.0f;
    float fy = (oj.y - oi.y) * 4.0f + 16.0f;
    // NaN in any coord fails the range test, matching the ok-masks
    if (fx >= 0.0f && fx < 32.0f && fy >= 0.0f && fy < 32.0f) {
      int cx = (int)fx, cy = (int)fy;   // trunc == floor for non-negative
      atomicMax(&win[cx * SGRID + cy], j);
    }
  }
  __syncthreads();

  // compact occupied cells into (g, j) lists
  for (int c = t; c < NCELL; c += 128) {
    int j = win[c];
    if (j >= 0) {
      int pos = atomicAdd(&s_cnt, 1);
      int cx = c >> 5, cy = c & 31;
      s_g[pos] = (short)(((cx >> 3) << 2) | (cy >> 3));
      s_j[pos] = (short)j;
    }
  }
  __syncthreads();

  // pooling: thread t owns hidden-channel h = t; static per-g accumulators
  // (16 uniform-branch passes over the ~26-entry list avoids dynamic reg
  // indexing / scratch spills)
  const int cnt = s_cnt;
  const int h = t;
  float acc[16];
#pragma unroll
  for (int g = 0; g < 16; ++g) {
    float a = 0.0f;
    for (int e = 0; e < cnt; ++e) {
      if ((int)s_g[e] == g) a += hidden[(int)s_j[e] * HID + h];
    }
    acc[g] = a;
  }

  float4* prow = (float4*)(P + (size_t)i * KDIM + h * 16);
  prow[0] = make_float4(acc[0],  acc[1],  acc[2],  acc[3]);
  prow[1] = make_float4(acc[4],  acc[5],  acc[6],  acc[7]);
  prow[2] = make_float4(acc[8],  acc[9],  acc[10], acc[11]);
  prow[3] = make_float4(acc[12], acc[13], acc[14], acc[15]);
}

// ---------------------------------------------------------------------------
// Kernel 2: WT[k][o] = W[o][k]   (32x32 LDS tile transpose, both sides
// coalesced). W is [128 x 2048] row-major.
// ---------------------------------------------------------------------------
__global__ __launch_bounds__(256) void transpose_kernel(
    const float* __restrict__ W, float* __restrict__ WT) {
  __shared__ float tile[32][33];
  const int kb = blockIdx.x * 32;
  const int ob = blockIdx.y * 32;
  const int tx = threadIdx.x & 31;
  const int ty = threadIdx.x >> 5;   // 0..7
#pragma unroll
  for (int r = 0; r < 4; ++r) {
    int o = ob + ty + r * 8;
    tile[ty + r * 8][tx] = W[o * KDIM + kb + tx];
  }
  __syncthreads();
#pragma unroll
  for (int r = 0; r < 4; ++r) {
    int k = kb + ty + r * 8;
    WT[k * OUT_DIM + ob + tx] = tile[tx][ty + r * 8];
  }
}

// ---------------------------------------------------------------------------
// Kernel 3: out = relu(P @ W^T + b), M=1024, K=2048, N=128. fp32 vector ALU
// (no fp32 MFMA on CDNA4). WT reads coalesced (L2-hot, 1MB); P reads are
// wave-uniform -> scalar loads feeding SGPR-operand FMAs.
// 128 blocks x 256 threads; each half-block (o = tid&127) owns 4 egos.
// ---------------------------------------------------------------------------
__global__ __launch_bounds__(256) void gemm_kernel(
    const float* __restrict__ P,
    const float* __restrict__ WT,
    const float* __restrict__ bias,
    float* __restrict__ out) {
  const int o  = threadIdx.x & 127;
  const int eh = threadIdx.x >> 7;              // 0 or 1
  const int i0 = blockIdx.x * 8 + eh * 4;       // 4 egos per half-block
  const float* __restrict__ p0 = P + (size_t)i0 * KDIM;

  float acc0 = 0.f, acc1 = 0.f, acc2 = 0.f, acc3 = 0.f;
#pragma unroll 8
  for (int k = 0; k < KDIM; ++k) {
    float wt = WT[k * OUT_DIM + o];
    acc0 = fmaf(p0[k],            wt, acc0);
    acc1 = fmaf(p0[KDIM + k],     wt, acc1);
    acc2 = fmaf(p0[2 * KDIM + k], wt, acc2);
    acc3 = fmaf(p0[3 * KDIM + k], wt, acc3);
  }
  const float bb = bias[o];
  out[(i0 + 0) * OUT_DIM + o] = fmaxf(acc0 + bb, 0.f);
  out[(i0 + 1) * OUT_DIM + o] = fmaxf(acc1 + bb, 0.f);
  out[(i0 + 2) * OUT_DIM + o] = fmaxf(acc2 + bb, 0.f);
  out[(i0 + 3) * OUT_DIM + o] = fmaxf(acc3 + bb, 0.f);
}

// ---------------------------------------------------------------------------
extern "C" void kernel_launch(void* const* d_in, const int* in_sizes, int n_in,
                              void* d_out, int out_size, void* d_ws, size_t ws_size,
                              hipStream_t stream) {
  const float* hidden = (const float*)d_in[0];
  // d_in[1] = obs1 (unused by the reference)
  const float* obs2 = (const float*)d_in[2];
  const float* W    = (const float*)d_in[3];
  const float* bias = (const float*)d_in[4];
  float* out = (float*)d_out;

  float* P  = (float*)d_ws;                                        // 8 MB
  float* WT = (float*)((char*)d_ws + (size_t)N_AGENTS * KDIM * 4); // 1 MB

  hipLaunchKernelGGL(pool_kernel, dim3(N_AGENTS), dim3(128), 0, stream,
                     hidden, obs2, P);
  hipLaunchKernelGGL(transpose_kernel, dim3(KDIM / 32, OUT_DIM / 32), dim3(256),
                     0, stream, W, WT);
  hipLaunchKernelGGL(gemm_kernel, dim3(N_AGENTS / 8), dim3(256), 0, stream,
                     P, WT, bias, out);
}

// Round 2
// 107.438 us; speedup vs baseline: 1.8751x; 1.8751x over previous
//
#include <hip/hip_runtime.h>
#include <math.h>

#define N_AGENTS 1024
#define HID      128
#define SGRID    32        // S
#define NCELL    1024      // S*S
#define KDIM     2048      // HID * NGRID * NGRID  (also the n-extent of Y)
#define OUT_DIM  128

// ---------------------------------------------------------------------------
// Algebraic restructure:
//   out[i,o] = relu(b[o] + sum_e Y[j_e, g_e, o])     (e = winner cells of ego i)
//   Y[j, g*128+o] = sum_h hidden[j][h] * W[o][h*16+g]   -- ego-independent GEMM
// This removes the 8 MB sparse P matrix and the per-ego 2048-K GEMM entirely.
// ---------------------------------------------------------------------------

// Kernel 1: WR2[h][g*128+o] = W[o][h*16+g].  32x32 LDS tile; reads coalesced
// over k (=h*16+g), writes coalesced over o.
__global__ __launch_bounds__(256) void reorder_kernel(
    const float* __restrict__ W, float* __restrict__ WR2) {
  __shared__ float tile[32][33];
  const int kb = blockIdx.x * 32;
  const int ob = blockIdx.y * 32;
  const int tx = threadIdx.x & 31;
  const int ty = threadIdx.x >> 5;   // 0..7
#pragma unroll
  for (int r = 0; r < 4; ++r) {
    int oloc = ty + r * 8;
    tile[oloc][tx] = W[(ob + oloc) * KDIM + kb + tx];
  }
  __syncthreads();
#pragma unroll
  for (int r = 0; r < 4; ++r) {
    int b = ty + r * 8;            // k index within tile
    int k = kb + b;
    int h = k >> 4, g = k & 15;
    WR2[h * KDIM + g * 128 + ob + tx] = tile[tx][b];
  }
}

// Kernel 2: Y[j][n] = sum_k hidden[j][k] * WR2[k][n],  M=1024 K=128 N=2048.
// 256 threads own one n-column each (w loads coalesced, L2-hot); each thread
// accumulates 16 j-rows; hidden addresses are wave-uniform -> scalar loads.
__global__ __launch_bounds__(256) void ygemm_kernel(
    const float* __restrict__ hidden,
    const float* __restrict__ WR2,
    float* __restrict__ Y) {
  const int n  = blockIdx.x * 256 + threadIdx.x;   // 0..2047
  const int j0 = blockIdx.y * 16;
  const float* __restrict__ w = WR2 + n;

  float acc[16];
#pragma unroll
  for (int j = 0; j < 16; ++j) acc[j] = 0.0f;

#pragma unroll 4
  for (int k = 0; k < HID; k += 4) {
    float w0 = w[(k + 0) * KDIM];
    float w1 = w[(k + 1) * KDIM];
    float w2 = w[(k + 2) * KDIM];
    float w3 = w[(k + 3) * KDIM];
#pragma unroll
    for (int j = 0; j < 16; ++j) {
      float4 h4 = *(const float4*)(hidden + (j0 + j) * HID + k);  // uniform -> s_load
      acc[j] = fmaf(h4.x, w0, acc[j]);
      acc[j] = fmaf(h4.y, w1, acc[j]);
      acc[j] = fmaf(h4.z, w2, acc[j]);
      acc[j] = fmaf(h4.w, w3, acc[j]);
    }
  }
#pragma unroll
  for (int j = 0; j < 16; ++j)
    Y[(size_t)(j0 + j) * KDIM + n] = acc[j];
}

// Kernel 3: per-ego winner scan + gather-sum of Y rows + bias + relu.
// Winner semantics: duplicate scatter indices resolve to LAST writer in index
// order (numpy scatter) == max j -> atomicMax on an LDS table (verified R0).
__global__ __launch_bounds__(128) void social_kernel(
    const float* __restrict__ obs2,
    const float* __restrict__ Y,
    const float* __restrict__ bias,
    float* __restrict__ out) {
  const int i = blockIdx.x;
  const int t = threadIdx.x;
  __shared__ int win[NCELL];
  __shared__ int s_cnt;
  __shared__ int s_off[NCELL];   // precomputed Y row offsets j*2048 + g*128

  for (int c = t; c < NCELL; c += 128) win[c] = -1;
  if (t == 0) s_cnt = 0;
  const float2* o2 = (const float2*)obs2;
  const float2 oi = o2[i];
  __syncthreads();

  for (int j = t; j < N_AGENTS; j += 128) {
    if (j == i) continue;
    float2 oj = o2[j];
    float fx = (oj.x - oi.x) * 4.0f + 16.0f;   // /0.25 exact
    float fy = (oj.y - oi.y) * 4.0f + 16.0f;
    // NaN coords fail the range test, matching the ok-masks
    if (fx >= 0.0f && fx < 32.0f && fy >= 0.0f && fy < 32.0f) {
      int cx = (int)fx, cy = (int)fy;          // trunc == floor (non-neg)
      atomicMax(&win[cx * SGRID + cy], j);
    }
  }
  __syncthreads();

  for (int c = t; c < NCELL; c += 128) {
    int j = win[c];
    if (j >= 0) {
      int cx = c >> 5, cy = c & 31;
      int g = ((cx >> 3) << 2) | (cy >> 3);
      int pos = atomicAdd(&s_cnt, 1);
      s_off[pos] = j * KDIM + g * 128;
    }
  }
  __syncthreads();

  const int cnt = s_cnt;
  float acc = bias[t];
  // 2-deep manual pipeline so the L2 gather latencies overlap
  int e = 0;
  for (; e + 2 <= cnt; e += 2) {
    int off0 = s_off[e], off1 = s_off[e + 1];
    float v0 = Y[off0 + t];
    float v1 = Y[off1 + t];
    acc += v0 + v1;
  }
  if (e < cnt) acc += Y[s_off[e] + t];

  out[i * OUT_DIM + t] = fmaxf(acc, 0.0f);
}

// ---------------------------------------------------------------------------
extern "C" void kernel_launch(void* const* d_in, const int* in_sizes, int n_in,
                              void* d_out, int out_size, void* d_ws, size_t ws_size,
                              hipStream_t stream) {
  const float* hidden = (const float*)d_in[0];
  // d_in[1] = obs1 (unused by the reference)
  const float* obs2 = (const float*)d_in[2];
  const float* W    = (const float*)d_in[3];
  const float* bias = (const float*)d_in[4];
  float* out = (float*)d_out;

  float* Y   = (float*)d_ws;                                        // 8 MB
  float* WR2 = (float*)((char*)d_ws + (size_t)N_AGENTS * KDIM * 4); // 1 MB

  hipLaunchKernelGGL(reorder_kernel, dim3(KDIM / 32, OUT_DIM / 32), dim3(256),
                     0, stream, W, WR2);
  hipLaunchKernelGGL(ygemm_kernel, dim3(KDIM / 256, N_AGENTS / 16), dim3(256),
                     0, stream, hidden, WR2, Y);
  hipLaunchKernelGGL(social_kernel, dim3(N_AGENTS), dim3(128), 0, stream,
                     obs2, Y, bias, out);
}

// Round 3
// 74.234 us; speedup vs baseline: 2.7139x; 1.4473x over previous
//
#include <hip/hip_runtime.h>
#include <math.h>

#define N_AGENTS 1024
#define HID      128
#define SGRID    32
#define NCELL    1024
#define KDIM     2048      // n-extent of Y = 16*128
#define OUT_DIM  128

typedef __attribute__((ext_vector_type(8))) short bf16x8;  // 8 bf16 in 4 VGPRs
typedef __attribute__((ext_vector_type(4))) float f32x4;

__device__ inline unsigned short f2bf(float x) {
  // round-to-nearest-even fp32 -> bf16
  unsigned int u = __float_as_uint(x);
  return (unsigned short)((u + 0x7FFFu + ((u >> 16) & 1u)) >> 16);
}

// ---------------------------------------------------------------------------
// Algebra (R1, kept): out[i,o] = relu(b[o] + sum_e Y[j_e, g_e*128+o]) where
// Y[j, g*128+o] = sum_h hidden[j][h] * W[o][h*16+g] is an ego-independent
// GEMM: [1024x128] @ [128x2048].  R2: run it on bf16 MFMA.
// ---------------------------------------------------------------------------

// Kernel 1 (prep): WB[g*128+o][h] = bf16(W[o][h*16+g])  (B operand, n-major,
// k-contiguous -> MFMA B-frag is a direct 16B load), and Ha = bf16(hidden).
// Blocks 0..127: one per W row o. Blocks 128..143: hidden convert.
__global__ __launch_bounds__(256) void prep_kernel(
    const float* __restrict__ W, const float* __restrict__ hidden,
    unsigned short* __restrict__ WB, unsigned short* __restrict__ Ha) {
  const int bid = blockIdx.x;
  const int t = threadIdx.x;
  if (bid < 128) {
    const int o = bid;
    const int g = t >> 4;            // 0..15
    const int h0 = (t & 15) * 8;     // 0,8,..,120
    const float* __restrict__ wrow = W + (size_t)o * KDIM;
    unsigned short tmp[8];
#pragma unroll
    for (int j = 0; j < 8; ++j) tmp[j] = f2bf(wrow[(h0 + j) * 16 + g]);
    unsigned short* dst = WB + (size_t)(g * 128 + o) * HID + h0;
    *(ushort4*)(dst)     = make_ushort4(tmp[0], tmp[1], tmp[2], tmp[3]);
    *(ushort4*)(dst + 4) = make_ushort4(tmp[4], tmp[5], tmp[6], tmp[7]);
  } else {
    const int i0 = (bid - 128) * 8192;
#pragma unroll
    for (int r = 0; r < 8; ++r) {
      int idx = i0 + r * 1024 + t * 4;
      float4 v = *(const float4*)(hidden + idx);
      *(ushort4*)(Ha + idx) = make_ushort4(f2bf(v.x), f2bf(v.y), f2bf(v.z), f2bf(v.w));
    }
  }
}

// Kernel 2: Y[j][n] = Ha[j][:] @ WB[n][:]  via v_mfma_f32_16x16x32_bf16.
// Block = 4 waves = 64(m) x 64(n) tile; wave = 16x64; K=128 -> 4 MFMA steps.
// Fragments loaded directly from global (no LDS): A[m=lane&15][k=quad*8+j],
// B[k=quad*8+j][n=lane&15]; C/D col=lane&15, row=quad*4+reg.
__global__ __launch_bounds__(256) void ygemm_kernel(
    const unsigned short* __restrict__ Ha,
    const unsigned short* __restrict__ WB,
    float* __restrict__ Y) {
  const int lane = threadIdx.x & 63;
  const int wave = threadIdx.x >> 6;   // 0..3
  const int quad = lane >> 4;          // 0..3
  const int l16  = lane & 15;
  const int m0 = blockIdx.y * 64 + wave * 16;
  const int n0 = blockIdx.x * 64;

  const unsigned short* pa  = Ha + (size_t)(m0 + l16) * HID + quad * 8;
  const unsigned short* pb0 = WB + (size_t)(n0 +  0 + l16) * HID + quad * 8;
  const unsigned short* pb1 = WB + (size_t)(n0 + 16 + l16) * HID + quad * 8;
  const unsigned short* pb2 = WB + (size_t)(n0 + 32 + l16) * HID + quad * 8;
  const unsigned short* pb3 = WB + (size_t)(n0 + 48 + l16) * HID + quad * 8;

  f32x4 acc0 = {0.f, 0.f, 0.f, 0.f};
  f32x4 acc1 = acc0, acc2 = acc0, acc3 = acc0;
#pragma unroll
  for (int s = 0; s < 4; ++s) {
    bf16x8 a  = *(const bf16x8*)(pa  + s * 32);
    bf16x8 b0 = *(const bf16x8*)(pb0 + s * 32);
    bf16x8 b1 = *(const bf16x8*)(pb1 + s * 32);
    bf16x8 b2 = *(const bf16x8*)(pb2 + s * 32);
    bf16x8 b3 = *(const bf16x8*)(pb3 + s * 32);
    acc0 = __builtin_amdgcn_mfma_f32_16x16x32_bf16(a, b0, acc0, 0, 0, 0);
    acc1 = __builtin_amdgcn_mfma_f32_16x16x32_bf16(a, b1, acc1, 0, 0, 0);
    acc2 = __builtin_amdgcn_mfma_f32_16x16x32_bf16(a, b2, acc2, 0, 0, 0);
    acc3 = __builtin_amdgcn_mfma_f32_16x16x32_bf16(a, b3, acc3, 0, 0, 0);
  }
  float* yrow = Y + (size_t)(m0 + quad * 4) * KDIM + n0 + l16;
#pragma unroll
  for (int r = 0; r < 4; ++r) {
    yrow[r * KDIM +  0] = acc0[r];
    yrow[r * KDIM + 16] = acc1[r];
    yrow[r * KDIM + 32] = acc2[r];
    yrow[r * KDIM + 48] = acc3[r];
  }
}

// Kernel 3: per-ego winner scan + 4-way-split gather of Y rows + bias + relu.
// Winner semantics: numpy scatter last-writer-wins == max j (verified R0).
__global__ __launch_bounds__(512) void social_kernel(
    const float* __restrict__ obs2,
    const float* __restrict__ Y,
    const float* __restrict__ bias,
    float* __restrict__ out) {
  const int i = blockIdx.x;
  const int t = threadIdx.x;
  __shared__ int win[NCELL];
  __shared__ int s_cnt;
  __shared__ int s_off[NCELL];      // Y offsets j*2048 + g*128
  __shared__ float part[3][128];

  for (int c = t; c < NCELL; c += 512) win[c] = -1;
  if (t == 0) s_cnt = 0;
  const float2* o2 = (const float2*)obs2;
  const float2 oi = o2[i];
  __syncthreads();

  for (int j = t; j < N_AGENTS; j += 512) {
    if (j == i) continue;
    float2 oj = o2[j];
    float fx = (oj.x - oi.x) * 4.0f + 16.0f;   // /0.25 exact
    float fy = (oj.y - oi.y) * 4.0f + 16.0f;
    // NaN coords fail the range test, matching the ok-masks
    if (fx >= 0.0f && fx < 32.0f && fy >= 0.0f && fy < 32.0f) {
      int cx = (int)fx, cy = (int)fy;          // trunc == floor (non-neg)
      atomicMax(&win[cx * SGRID + cy], j);
    }
  }
  __syncthreads();

  for (int c = t; c < NCELL; c += 512) {
    int j = win[c];
    if (j >= 0) {
      int cx = c >> 5, cy = c & 31;
      int g = ((cx >> 3) << 2) | (cy >> 3);
      int pos = atomicAdd(&s_cnt, 1);
      s_off[pos] = j * KDIM + g * 128;
    }
  }
  __syncthreads();

  const int cnt = s_cnt;
  const int o = t & 127;
  const int par = t >> 7;           // 4 partitions over winner entries
  float a0 = 0.f, a1 = 0.f;
  int e = par;
  for (; e + 4 < cnt; e += 8) {     // 2 in flight per partition
    a0 += Y[s_off[e] + o];
    a1 += Y[s_off[e + 4] + o];
  }
  for (; e < cnt; e += 4) a0 += Y[s_off[e] + o];
  float a = a0 + a1;
  if (par) part[par - 1][o] = a;
  __syncthreads();
  if (t < 128) {
    float acc = bias[t] + a + part[0][t] + part[1][t] + part[2][t];
    out[i * OUT_DIM + t] = fmaxf(acc, 0.0f);
  }
}

// ---------------------------------------------------------------------------
extern "C" void kernel_launch(void* const* d_in, const int* in_sizes, int n_in,
                              void* d_out, int out_size, void* d_ws, size_t ws_size,
                              hipStream_t stream) {
  const float* hidden = (const float*)d_in[0];
  // d_in[1] = obs1 (unused by the reference)
  const float* obs2 = (const float*)d_in[2];
  const float* W    = (const float*)d_in[3];
  const float* bias = (const float*)d_in[4];
  float* out = (float*)d_out;

  float*          Y  = (float*)d_ws;                                  // 8 MB
  unsigned short* WB = (unsigned short*)((char*)d_ws + 8u * 1024 * 1024);   // 0.5 MB
  unsigned short* Ha = (unsigned short*)((char*)d_ws + 8704u * 1024);       // 0.25 MB

  hipLaunchKernelGGL(prep_kernel, dim3(144), dim3(256), 0, stream,
                     W, hidden, WB, Ha);
  hipLaunchKernelGGL(ygemm_kernel, dim3(KDIM / 64, N_AGENTS / 64), dim3(256),
                     0, stream, Ha, WB, Y);
  hipLaunchKernelGGL(social_kernel, dim3(N_AGENTS), dim3(512), 0, stream,
                     obs2, Y, bias, out);
}